// Round 5
// baseline (679.923 us; speedup 1.0000x reference)
//
#include <hip/hip_runtime.h>
#include <hip/hip_bf16.h>

typedef __hip_bfloat16 bf16;
typedef __attribute__((ext_vector_type(8))) short short8;
typedef __attribute__((ext_vector_type(4))) short short4v;
typedef __attribute__((ext_vector_type(4))) float float4v;

__device__ __forceinline__ short f2bs(float f){
    union { bf16 h; short s; } u; u.h = __float2bfloat16(f); return u.s;
}
__device__ __forceinline__ float bs2f(short s){
    return __uint_as_float(((unsigned)(unsigned short)s) << 16);
}
__device__ __forceinline__ float gelu_exact(float x){
    return 0.5f * x * (1.0f + erff(x * 0.70710678118654752440f));
}
__device__ __forceinline__ short8 load_w8(const float* p){
    float4v w0 = *(const float4v*)p;
    float4v w1 = *(const float4v*)(p + 4);
    short8 r;
    r[0]=f2bs(w0[0]); r[1]=f2bs(w0[1]); r[2]=f2bs(w0[2]); r[3]=f2bs(w0[3]);
    r[4]=f2bs(w1[0]); r[5]=f2bs(w1[1]); r[6]=f2bs(w1[2]); r[7]=f2bs(w1[3]);
    return r;
}
#define MFMA(a,b,c) __builtin_amdgcn_mfma_f32_16x16x32_bf16((a),(b),(c),0,0,0)

#define HW 16384
#define NPLANE 1048576
#define EPS 1e-5f
#define LS 72             // LDS row stride in bf16 (144 B)

// ---------------- Kernel 1: per-(b,c) LN1 stats over H*W ----------------
__global__ __launch_bounds__(256) void k_stats(const float* __restrict__ x,
                                               float* __restrict__ mu,
                                               float* __restrict__ rinv){
    int bc = blockIdx.x;
    const float* p = x + (size_t)bc * HW;
    float s = 0.f, ss = 0.f;
    for (int i = threadIdx.x; i < HW; i += 256){
        float v = p[i]; s += v; ss += v*v;
    }
    __shared__ float rs[256], rss[256];
    rs[threadIdx.x] = s; rss[threadIdx.x] = ss; __syncthreads();
    for (int st = 128; st > 0; st >>= 1){
        if (threadIdx.x < st){ rs[threadIdx.x] += rs[threadIdx.x+st]; rss[threadIdx.x] += rss[threadIdx.x+st]; }
        __syncthreads();
    }
    if (threadIdx.x == 0){
        float m = rs[0] * (1.f/HW);
        float v = rss[0] * (1.f/HW) - m*m;
        mu[bc] = m; rinv[bc] = rsqrtf(v + EPS);
    }
}

// ---------------- Kernel 2: LN1 + 1x1 conv (MFMA) + LN2 partial sums ----------------
__global__ __launch_bounds__(256) void k_conv(const float* __restrict__ x,
                                              const float* __restrict__ mu,
                                              const float* __restrict__ rinv,
                                              const float* __restrict__ g1a, const float* __restrict__ b1a,
                                              const float* __restrict__ w1,  const float* __restrict__ cb1,
                                              const float* __restrict__ g1b, const float* __restrict__ b1b,
                                              const float* __restrict__ w2,  const float* __restrict__ cb2,
                                              float* __restrict__ y1, float* __restrict__ y2,
                                              float* __restrict__ sum2, float* __restrict__ sumsq2){
    int blk = blockIdx.x;          // 16*256 blocks
    int b = blk >> 8; int tile = blk & 255; int hw0 = tile * 64;
    __shared__ __align__(16) short xn_bf[64*LS];
    __shared__ float rowsumS[2][64];
    const int tid = threadIdx.x;
    const int wq = tid >> 6, lane = tid & 63, qd = lane >> 4, col = lane & 15;
    const float4v zf = {0.f,0.f,0.f,0.f};

    for (int i = tid; i < 1024; i += 256){
        int c = i >> 4, p0 = (i & 15) * 4;
        int bc = b*64 + c;
        float m = mu[bc], rv = rinv[bc];
        float4v v = *(const float4v*)(x + (size_t)bc*HW + hw0 + p0);
        #pragma unroll
        for (int k = 0; k < 4; k++) xn_bf[(p0+k)*LS + c] = f2bs((v[k] - m) * rv);
    }
    if (tid < 128){
        int br = tid >> 6, o = tid & 63;
        const float* W = br ? w2 : w1;
        float s = 0.f;
        for (int c = 0; c < 64; c++) s += W[o*64 + c];
        rowsumS[br][o] = s;
    }
    __syncthreads();

    #pragma unroll
    for (int br = 0; br < 2; br++){
        const float* W  = br ? w2  : w1;
        const float* cb = br ? cb2 : cb1;
        const float* gp = br ? g1b : g1a;
        const float* bp = br ? b1b : b1a;
        float* y = br ? y2 : y1;
        short8 a0 = load_w8(W + (size_t)(16*wq + col)*64 + 8*qd);
        short8 a1 = load_w8(W + (size_t)(16*wq + col)*64 + 32 + 8*qd);
        float cbv[4], rsv[4];
        #pragma unroll
        for (int r = 0; r < 4; r++){
            int o = 16*wq + 4*qd + r;
            cbv[r] = cb[o]; rsv[r] = rowsumS[br][o];
        }
        float sacc[4] = {0.f,0.f,0.f,0.f};
        float ssacc[4] = {0.f,0.f,0.f,0.f};
        #pragma unroll
        for (int jn = 0; jn < 4; jn++){
            short8 bx0 = *(const short8*)&xn_bf[(16*jn + col)*LS + 8*qd];
            short8 bx1 = *(const short8*)&xn_bf[(16*jn + col)*LS + 32 + 8*qd];
            float4v acc = zf;
            acc = MFMA(a0, bx0, acc);
            acc = MFMA(a1, bx1, acc);
            int hw = hw0 + 16*jn + col;
            float gl = gp[hw], bl = bp[hw];
            #pragma unroll
            for (int r = 0; r < 4; r++){
                int o = 16*wq + 4*qd + r;
                float val = gl*acc[r] + bl*rsv[r] + cbv[r];
                y[(size_t)(b*64 + o)*HW + hw] = val;
                sacc[r] += val; ssacc[r] += val*val;
            }
        }
        // reduce over col within 16-lane group, one atomic per (o)
        #pragma unroll
        for (int r = 0; r < 4; r++){
            float s = sacc[r], ss = ssacc[r];
            s += __shfl_xor(s, 1); ss += __shfl_xor(ss, 1);
            s += __shfl_xor(s, 2); ss += __shfl_xor(ss, 2);
            s += __shfl_xor(s, 4); ss += __shfl_xor(ss, 4);
            s += __shfl_xor(s, 8); ss += __shfl_xor(ss, 8);
            if (col == 0){
                int o = 16*wq + 4*qd + r;
                atomicAdd(&sum2[br*1024 + b*64 + o], s);
                atomicAdd(&sumsq2[br*1024 + b*64 + o], ss);
            }
        }
    }
}

// ---------------- Kernel 3: finalize LN2 stats ----------------
__global__ __launch_bounds__(256) void k_finstat(const float* __restrict__ sum2,
                                                 const float* __restrict__ sumsq2,
                                                 float* __restrict__ mu2,
                                                 float* __restrict__ rinv2){
    int i = blockIdx.x * 256 + threadIdx.x;    // 2048
    float m = sum2[i] * (1.f/HW);
    float var = sumsq2[i] * (1.f/HW) - m*m;
    mu2[i] = m; rinv2[i] = rsqrtf(var + EPS);
}

// ---------------- Kernel 4: LN2+GELU -> attention + LAM + proj + MLP (fused) ----------------
// x1 (= y1) lives in d_out; final output written in place over x1.
__global__ __launch_bounds__(256) void k_attn(float* __restrict__ x1, const float* __restrict__ x2,
                                              const float* __restrict__ mu2, const float* __restrict__ rinv2,
                                              const float* __restrict__ g2x1, const float* __restrict__ b2x1,
                                              const float* __restrict__ g2x2, const float* __restrict__ b2x2,
                                              const float* __restrict__ pos1, const float* __restrict__ pos2,
                                              const float* __restrict__ qw, const float* __restrict__ qb,
                                              const float* __restrict__ kvw, const float* __restrict__ kvb,
                                              const float* __restrict__ rpb, const float* __restrict__ gammap,
                                              const float* __restrict__ pw, const float* __restrict__ pb,
                                              const float* __restrict__ n2g, const float* __restrict__ n2b,
                                              const float* __restrict__ fw1, const float* __restrict__ fb1,
                                              const float* __restrict__ fw2, const float* __restrict__ fb2){
    // XCD swizzle: bits [2:0]=hy[2:0], [3]=wx[0], [7:4]=b, [8]=hy[3], [11:9]=wx[3:1]
    // => the two windows sharing each 64B line (wx even/odd) are 8 apart in
    //    blockIdx (same XCD under %8 round-robin) and issue back-to-back.
    int B = blockIdx.x;
    int hy = (B & 7) | ((B >> 5) & 8);
    int wx = (((B >> 9) & 7) << 1) | ((B >> 3) & 1);
    int b  = (B >> 4) & 15;

    __shared__ __align__(16) char smem[51744];
    short* bufA = (short*)smem;                    // 9216  X2w -> X1w
    short* bufK = (short*)(smem + 9216);           // 9216  K -> O2
    short* bufV = (short*)(smem + 18432);          // 9216  VT -> OT
    short* bufQ = (short*)(smem + 27648);          // 9216  Q -> h1 (MLP)
    short* bufP = (short*)(smem + 36864);          // 9216  P -> XO -> tn (MLP)
    float* rpb_lds = (float*)(smem + 46080);       // 3600
    float* energyS = (float*)(smem + 49696);       // 1024
    short* soft_bf = (short*)(smem + 50720);       // 1024
    // MLP-tail aliases (all source regions dead by then):
    float* XOf  = (float*)smem;                    // 64x65 fp32 (A+K regions)
    float* sumS = (float*)(smem + 49696);          // 4x64 (energy)
    float* sqS  = (float*)(smem + 50720);          // 4x64 (soft)
    float* muS  = (float*)(smem + 46080);          // 64   (rpb)
    float* rinvS= (float*)(smem + 46336);          // 64

    const int tid = threadIdx.x;
    const int wq = tid >> 6, lane = tid & 63, qd = lane >> 4, col = lane & 15;
    size_t base = (size_t)b * NPLANE;
    #define HWOF(t) ((hy*8 + ((t)>>3))*128 + wx*8 + ((t)&7))

    const float4v zf = {0.f,0.f,0.f,0.f};
    const short8 zero8 = {0,0,0,0,0,0,0,0};

    for (int i = tid; i < 900; i += 256) rpb_lds[i] = rpb[i];

    // ---- load X2: LN2 + GELU + pos2 -> bufA ----
    for (int i = tid; i < 1024; i += 256){
        int c = i >> 4, t0 = (i & 15) * 4;
        int bc = b*64 + c;
        float m2 = mu2[1024 + bc], r2 = rinv2[1024 + bc];
        float4v v = *(const float4v*)(x2 + base + (size_t)c*HW + HWOF(t0));
        #pragma unroll
        for (int k = 0; k < 4; k++){
            int hw = HWOF(t0+k);
            float nv = (v[k] - m2) * r2 * g2x2[hw] + b2x2[hw];
            bufA[(t0+k)*LS + c] = f2bs(gelu_exact(nv) + pos2[(t0+k)*64 + c]);
        }
    }
    __syncthreads();

    // ---- VT = Wv · X2^T ----
    {
        float bvr[4];
        #pragma unroll
        for (int r = 0; r < 4; r++) bvr[r] = kvb[64 + 16*wq + 4*qd + r];
        short8 a0 = load_w8(kvw + (size_t)(64 + 16*wq + col)*64 + 8*qd);
        short8 a1 = load_w8(kvw + (size_t)(64 + 16*wq + col)*64 + 32 + 8*qd);
        #pragma unroll
        for (int jn = 0; jn < 4; jn++){
            int u = 16*jn + col;
            short8 b0 = *(const short8*)&bufA[u*LS + 8*qd];
            short8 b1 = *(const short8*)&bufA[u*LS + 32 + 8*qd];
            float4v acc = zf;
            acc = MFMA(a0, b0, acc);
            acc = MFMA(a1, b1, acc);
            #pragma unroll
            for (int r = 0; r < 4; r++)
                bufV[(16*wq + 4*qd + r)*LS + u] = f2bs(acc[r] + bvr[r]);
        }
    }
    // ---- K = X2 · Wk^T ----
    {
        short8 ax0 = *(const short8*)&bufA[(16*wq + col)*LS + 8*qd];
        short8 ax1 = *(const short8*)&bufA[(16*wq + col)*LS + 32 + 8*qd];
        #pragma unroll
        for (int jn = 0; jn < 4; jn++){
            int co = 16*jn + col;
            short8 b0 = load_w8(kvw + (size_t)co*64 + 8*qd);
            short8 b1 = load_w8(kvw + (size_t)co*64 + 32 + 8*qd);
            float4v acc = zf;
            acc = MFMA(ax0, b0, acc);
            acc = MFMA(ax1, b1, acc);
            float kb = kvb[co];
            #pragma unroll
            for (int r = 0; r < 4; r++)
                bufK[(16*wq + 4*qd + r)*LS + co] = f2bs(acc[r] + kb);
        }
    }
    __syncthreads();

    // ---- load X1: LN2 + GELU + pos1 -> bufA ----
    for (int i = tid; i < 1024; i += 256){
        int c = i >> 4, t0 = (i & 15) * 4;
        int bc = b*64 + c;
        float m2 = mu2[bc], r2 = rinv2[bc];
        float4v v = *(const float4v*)(x1 + base + (size_t)c*HW + HWOF(t0));
        #pragma unroll
        for (int k = 0; k < 4; k++){
            int hw = HWOF(t0+k);
            float nv = (v[k] - m2) * r2 * g2x1[hw] + b2x1[hw];
            bufA[(t0+k)*LS + c] = f2bs(gelu_exact(nv) + pos1[(t0+k)*64 + c]);
        }
    }
    __syncthreads();

    // ---- Q = 0.25 * (X1 · Wq^T + qb) ----
    {
        short8 ax0 = *(const short8*)&bufA[(16*wq + col)*LS + 8*qd];
        short8 ax1 = *(const short8*)&bufA[(16*wq + col)*LS + 32 + 8*qd];
        #pragma unroll
        for (int jn = 0; jn < 4; jn++){
            int co = 16*jn + col;
            short8 b0 = load_w8(qw + (size_t)co*64 + 8*qd);
            short8 b1 = load_w8(qw + (size_t)co*64 + 32 + 8*qd);
            float4v acc = zf;
            acc = MFMA(ax0, b0, acc);
            acc = MFMA(ax1, b1, acc);
            float qbv = qb[co];
            #pragma unroll
            for (int r = 0; r < 4; r++)
                bufQ[(16*wq + 4*qd + r)*LS + co] = f2bs((acc[r] + qbv) * 0.25f);
        }
    }
    __syncthreads();

    int idx_t[4][4];
    #pragma unroll
    for (int jn = 0; jn < 4; jn++){
        int u = 16*jn + col; int uy = u >> 3, ux = u & 7;
        #pragma unroll
        for (int r = 0; r < 4; r++){
            int t = 16*wq + 4*qd + r;
            idx_t[jn][r] = ((t>>3) - uy + 7)*15 + ((t&7) - ux + 7);
        }
    }

    // ---- head loop: S -> softmax -> P -> PV -> OT/O2 ----
    for (int h = 0; h < 4; h++){
        short8 aq = *(const short8*)&bufQ[(16*wq + col)*LS + h*16 + (qd & 1)*8];
        if (qd >= 2) aq = zero8;
        float4v acc_s[4];
        #pragma unroll
        for (int jn = 0; jn < 4; jn++){
            int u = 16*jn + col;
            short8 bk = *(const short8*)&bufK[u*LS + h*16 + (qd & 1)*8];
            acc_s[jn] = MFMA(aq, bk, zf);
        }
        float pr[4][4];
        #pragma unroll
        for (int jn = 0; jn < 4; jn++)
            #pragma unroll
            for (int r = 0; r < 4; r++)
                pr[jn][r] = acc_s[jn][r] + rpb_lds[idx_t[jn][r]*4 + h];
        #pragma unroll
        for (int r = 0; r < 4; r++){
            float m = fmaxf(fmaxf(pr[0][r], pr[1][r]), fmaxf(pr[2][r], pr[3][r]));
            m = fmaxf(m, __shfl_xor(m, 1)); m = fmaxf(m, __shfl_xor(m, 2));
            m = fmaxf(m, __shfl_xor(m, 4)); m = fmaxf(m, __shfl_xor(m, 8));
            float s = 0.f;
            #pragma unroll
            for (int jn = 0; jn < 4; jn++){ pr[jn][r] = __expf(pr[jn][r] - m); s += pr[jn][r]; }
            s += __shfl_xor(s, 1); s += __shfl_xor(s, 2);
            s += __shfl_xor(s, 4); s += __shfl_xor(s, 8);
            float rc = 1.f / s;
            #pragma unroll
            for (int jn = 0; jn < 4; jn++)
                bufP[(16*wq + 4*qd + r)*LS + 16*jn + col] = f2bs(pr[jn][r] * rc);
        }
        __syncthreads();
        short8 ap0 = *(const short8*)&bufP[(16*wq + col)*LS + 8*qd];
        short8 ap1 = *(const short8*)&bufP[(16*wq + col)*LS + 32 + 8*qd];
        short8 bv0 = *(const short8*)&bufV[(h*16 + col)*LS + 8*qd];
        short8 bv1 = *(const short8*)&bufV[(h*16 + col)*LS + 32 + 8*qd];
        float4v acc_o = zf;
        acc_o = MFMA(ap0, bv0, acc_o);
        acc_o = MFMA(ap1, bv1, acc_o);
        __syncthreads();
        short4v ot;
        #pragma unroll
        for (int r = 0; r < 4; r++) ot[r] = f2bs(acc_o[r]);
        *(short4v*)&bufV[(h*16 + col)*LS + 16*wq + 4*qd] = ot;
        #pragma unroll
        for (int r = 0; r < 4; r++)
            bufK[(16*wq + 4*qd + r)*LS + h*16 + col] = ot[r];
    }
    __syncthreads();

    // ---- energy = Y Y^T (16x16, K=256) ----
    {
        float4v acc_e = zf;
        #pragma unroll
        for (int h = 0; h < 4; h++){
            short8 f0 = *(const short8*)&bufV[(h*16 + col)*LS + 8*qd];
            short8 f1 = *(const short8*)&bufV[(h*16 + col)*LS + 32 + 8*qd];
            acc_e = MFMA(f0, f0, acc_e);
            acc_e = MFMA(f1, f1, acc_e);
        }
        if (wq == 0){
            #pragma unroll
            for (int r = 0; r < 4; r++) energyS[(4*qd + r)*16 + col] = acc_e[r];
        }
    }
    __syncthreads();
    if (tid < 16){
        int i = tid; float m = -1e30f;
        for (int j = 0; j < 16; j++) m = fmaxf(m, energyS[i*16 + j]);
        float s = 0.f; float e[16];
        for (int j = 0; j < 16; j++){ e[j] = __expf(energyS[i*16 + j] - m); s += e[j]; }
        float rc = 1.f / s;
        for (int j = 0; j < 16; j++) soft_bf[i*32 + j] = f2bs(e[j] * rc);
        for (int j = 0; j < 16; j++) soft_bf[i*32 + 16 + j] = 0;
    }
    __syncthreads();

    // ---- lam (per wave: head h=wq) + assemble XO -> bufP ----
    {
        int h = wq;
        float gam = gammap[0];
        short8 asf = *(const short8*)&soft_bf[col*32 + 8*qd];
        #pragma unroll
        for (int jn = 0; jn < 4; jn++){
            int t = 16*jn + col;
            short8 bo = *(const short8*)&bufK[t*LS + h*16 + (qd & 1)*8];
            float4v acc = MFMA(asf, bo, zf);
            short4v qv = *(const short4v*)&bufQ[t*LS + h*16 + 4*qd];
            short4v xv = *(const short4v*)&bufA[t*LS + h*16 + 4*qd];
            short4v pk;
            #pragma unroll
            for (int r = 0; r < 4; r++){
                float ot = bs2f(bufV[(h*16 + 4*qd + r)*LS + t]);
                float xo = gam*acc[r] + ot + bs2f(qv[r]) + bs2f(xv[r]);
                pk[r] = f2bs(xo);
            }
            *(short4v*)&bufP[t*LS + h*16 + 4*qd] = pk;
        }
    }
    __syncthreads();

    // ---- proj: XO · Wp^T + pb -> XOf (fp32 LDS, aliases bufA+bufK) ----
    {
        short8 a0 = *(const short8*)&bufP[(16*wq + col)*LS + 8*qd];
        short8 a1 = *(const short8*)&bufP[(16*wq + col)*LS + 32 + 8*qd];
        #pragma unroll
        for (int jn = 0; jn < 4; jn++){
            int c = 16*jn + col;
            short8 b0 = load_w8(pw + (size_t)c*64 + 8*qd);
            short8 b1 = load_w8(pw + (size_t)c*64 + 32 + 8*qd);
            float4v acc = zf;
            acc = MFMA(a0, b0, acc);
            acc = MFMA(a1, b1, acc);
            float pbv = pb[c];
            #pragma unroll
            for (int r = 0; r < 4; r++)
                XOf[(16*wq + 4*qd + r)*65 + c] = acc[r] + pbv;
        }
    }
    __syncthreads();

    // ================= fused channel-MLP =================
    // stats over c per token
    {
        int p = tid & 63, qg = tid >> 6;
        float s = 0.f, ss = 0.f;
        #pragma unroll
        for (int j = 0; j < 16; j++){ float v = XOf[p*65 + qg*16 + j]; s += v; ss += v*v; }
        sumS[qg*64 + p] = s; sqS[qg*64 + p] = ss;
    }
    __syncthreads();
    if (tid < 64){
        float s  = sumS[tid] + sumS[64+tid] + sumS[128+tid] + sumS[192+tid];
        float ss = sqS[tid]  + sqS[64+tid]  + sqS[128+tid]  + sqS[192+tid];
        float m = s * (1.f/64.f);
        float var = ss * (1.f/64.f) - m*m;
        muS[tid] = m; rinvS[tid] = rsqrtf(var + EPS);
    }
    __syncthreads();
    // tn -> bufP (bf16)
    {
        int p = tid & 63, qg = tid >> 6;
        float m = muS[p], rv = rinvS[p];
        #pragma unroll
        for (int j = 0; j < 16; j++){
            int c = qg*16 + j;
            bufP[p*LS + c] = f2bs((XOf[p*65 + c] - m) * rv * n2g[c] + n2b[c]);
        }
    }
    __syncthreads();
    // GEMM1: h1 = gelu(tn @ W1^T + fb1) -> bufQ
    {
        short8 a0 = *(const short8*)&bufP[(16*wq + col)*LS + 8*qd];
        short8 a1 = *(const short8*)&bufP[(16*wq + col)*LS + 32 + 8*qd];
        #pragma unroll
        for (int jn = 0; jn < 4; jn++){
            int j = 16*jn + col;
            short8 f0 = load_w8(fw1 + (size_t)j*64 + 8*qd);
            short8 f1 = load_w8(fw1 + (size_t)j*64 + 32 + 8*qd);
            float4v acc = zf;
            acc = MFMA(a0, f0, acc);
            acc = MFMA(a1, f1, acc);
            float bv = fb1[j];
            #pragma unroll
            for (int r = 0; r < 4; r++)
                bufQ[(16*wq + 4*qd + r)*LS + j] = f2bs(gelu_exact(acc[r] + bv));
        }
    }
    __syncthreads();
    // GEMM2: out = xo + h1 @ W2^T + fb2 -> global (in place over x1)
    {
        short8 a0 = *(const short8*)&bufQ[(16*wq + col)*LS + 8*qd];
        short8 a1 = *(const short8*)&bufQ[(16*wq + col)*LS + 32 + 8*qd];
        #pragma unroll
        for (int jn = 0; jn < 4; jn++){
            int c2 = 16*jn + col;
            short8 f0 = load_w8(fw2 + (size_t)c2*64 + 8*qd);
            short8 f1 = load_w8(fw2 + (size_t)c2*64 + 32 + 8*qd);
            float4v acc = zf;
            acc = MFMA(a0, f0, acc);
            acc = MFMA(a1, f1, acc);
            float bv = fb2[c2];
            float4v ov;
            #pragma unroll
            for (int r = 0; r < 4; r++)
                ov[r] = acc[r] + bv + XOf[(16*wq + 4*qd + r)*65 + c2];
            int t0 = 16*wq + 4*qd;
            *(float4v*)(x1 + base + (size_t)c2*HW + HWOF(t0)) = ov;
        }
    }
    #undef HWOF
}

extern "C" void kernel_launch(void* const* d_in, const int* in_sizes, int n_in,
                              void* d_out, int out_size, void* d_ws, size_t ws_size,
                              hipStream_t stream){
    const float* x        = (const float*)d_in[0];
    const float* l1_g1    = (const float*)d_in[1];
    const float* l1_b1    = (const float*)d_in[2];
    const float* l1_cw    = (const float*)d_in[3];
    const float* l1_cb    = (const float*)d_in[4];
    const float* l1_g2    = (const float*)d_in[5];
    const float* l1_b2    = (const float*)d_in[6];
    const float* l2_g1    = (const float*)d_in[7];
    const float* l2_b1    = (const float*)d_in[8];
    const float* l2_cw    = (const float*)d_in[9];
    const float* l2_cb    = (const float*)d_in[10];
    const float* l2_g2    = (const float*)d_in[11];
    const float* l2_b2    = (const float*)d_in[12];
    const float* pos1     = (const float*)d_in[13];
    const float* pos2     = (const float*)d_in[14];
    const float* q_w      = (const float*)d_in[15];
    const float* q_b      = (const float*)d_in[16];
    const float* kv_w     = (const float*)d_in[17];
    const float* kv_b     = (const float*)d_in[18];
    const float* rpb      = (const float*)d_in[19];
    const float* gamma    = (const float*)d_in[20];
    const float* proj_w   = (const float*)d_in[21];
    const float* proj_b   = (const float*)d_in[22];
    const float* norm2_g  = (const float*)d_in[23];
    const float* norm2_b  = (const float*)d_in[24];
    const float* fc1_w    = (const float*)d_in[25];
    const float* fc1_b    = (const float*)d_in[26];
    const float* fc2_w    = (const float*)d_in[27];
    const float* fc2_b    = (const float*)d_in[28];

    float* out = (float*)d_out;                // y1 -> final, in place

    float* y2    = (float*)d_ws;               // 16*NPLANE floats (67 MB)
    float* mu1   = y2 + (size_t)16*NPLANE;
    float* rinv1 = mu1 + 1024;
    float* sum2  = rinv1 + 1024;               // [2][1024]
    float* ssq2  = sum2 + 2048;                // [2][1024]
    float* mu2   = ssq2 + 2048;                // [2][1024]
    float* rinv2 = mu2 + 2048;                 // [2][1024]

    hipMemsetAsync(sum2, 0, 4096 * sizeof(float), stream);   // zero sum2+ssq2
    k_stats  <<<1024, 256, 0, stream>>>(x, mu1, rinv1);
    k_conv   <<<4096, 256, 0, stream>>>(x, mu1, rinv1,
                                        l1_g1, l1_b1, l1_cw, l1_cb,
                                        l2_g1, l2_b1, l2_cw, l2_cb, out, y2,
                                        sum2, ssq2);
    k_finstat<<<8, 256, 0, stream>>>(sum2, ssq2, mu2, rinv2);
    k_attn   <<<4096, 256, 0, stream>>>(out, y2, mu2, rinv2,
                                        l1_g2, l1_b2, l2_g2, l2_b2,
                                        pos1, pos2, q_w, q_b, kv_w, kv_b,
                                        rpb, gamma, proj_w, proj_b,
                                        norm2_g, norm2_b, fc1_w, fc1_b, fc2_w, fc2_b);
}

// Round 6
// 561.250 us; speedup vs baseline: 1.2114x; 1.2114x over previous
//
#include <hip/hip_runtime.h>
#include <hip/hip_bf16.h>

typedef __hip_bfloat16 bf16;
typedef __attribute__((ext_vector_type(8))) short short8;
typedef __attribute__((ext_vector_type(4))) short short4v;
typedef __attribute__((ext_vector_type(4))) float float4v;

__device__ __forceinline__ short f2bs(float f){
    union { bf16 h; short s; } u; u.h = __float2bfloat16(f); return u.s;
}
__device__ __forceinline__ float bs2f(short s){
    return __uint_as_float(((unsigned)(unsigned short)s) << 16);
}
__device__ __forceinline__ float gelu_exact(float x){
    return 0.5f * x * (1.0f + erff(x * 0.70710678118654752440f));
}
__device__ __forceinline__ short8 load_w8(const float* p){
    float4v w0 = *(const float4v*)p;
    float4v w1 = *(const float4v*)(p + 4);
    short8 r;
    r[0]=f2bs(w0[0]); r[1]=f2bs(w0[1]); r[2]=f2bs(w0[2]); r[3]=f2bs(w0[3]);
    r[4]=f2bs(w1[0]); r[5]=f2bs(w1[1]); r[6]=f2bs(w1[2]); r[7]=f2bs(w1[3]);
    return r;
}
#define MFMA(a,b,c) __builtin_amdgcn_mfma_f32_16x16x32_bf16((a),(b),(c),0,0,0)

#define HW 16384
#define NPLANE 1048576
#define EPS 1e-5f
#define LS 72             // LDS row stride in bf16 (144 B)

// ---------------- Kernel 1: per-(b,c) LN1 stats over H*W ----------------
__global__ __launch_bounds__(256) void k_stats(const float* __restrict__ x,
                                               float* __restrict__ mu,
                                               float* __restrict__ rinv){
    int bc = blockIdx.x;
    const float* p = x + (size_t)bc * HW;
    float s = 0.f, ss = 0.f;
    for (int i = threadIdx.x; i < HW; i += 256){
        float v = p[i]; s += v; ss += v*v;
    }
    __shared__ float rs[256], rss[256];
    rs[threadIdx.x] = s; rss[threadIdx.x] = ss; __syncthreads();
    for (int st = 128; st > 0; st >>= 1){
        if (threadIdx.x < st){ rs[threadIdx.x] += rs[threadIdx.x+st]; rss[threadIdx.x] += rss[threadIdx.x+st]; }
        __syncthreads();
    }
    if (threadIdx.x == 0){
        float m = rs[0] * (1.f/HW);
        float v = rss[0] * (1.f/HW) - m*m;
        mu[bc] = m; rinv[bc] = rsqrtf(v + EPS);
    }
}

// ---------------- Kernel 2: LN1 + 1x1 conv, both branches (MFMA) ----------------
__global__ __launch_bounds__(256) void k_conv(const float* __restrict__ x,
                                              const float* __restrict__ mu,
                                              const float* __restrict__ rinv,
                                              const float* __restrict__ g1a, const float* __restrict__ b1a,
                                              const float* __restrict__ w1,  const float* __restrict__ cb1,
                                              const float* __restrict__ g1b, const float* __restrict__ b1b,
                                              const float* __restrict__ w2,  const float* __restrict__ cb2,
                                              float* __restrict__ y1, float* __restrict__ y2){
    int blk = blockIdx.x;          // 16*256 blocks
    int b = blk >> 8; int tile = blk & 255; int hw0 = tile * 64;
    __shared__ __align__(16) short xn_bf[64*LS];
    __shared__ float rowsumS[2][64];
    const int tid = threadIdx.x;
    const int wq = tid >> 6, lane = tid & 63, qd = lane >> 4, col = lane & 15;
    const float4v zf = {0.f,0.f,0.f,0.f};

    for (int i = tid; i < 1024; i += 256){
        int c = i >> 4, p0 = (i & 15) * 4;
        int bc = b*64 + c;
        float m = mu[bc], rv = rinv[bc];
        float4v v = *(const float4v*)(x + (size_t)bc*HW + hw0 + p0);
        #pragma unroll
        for (int k = 0; k < 4; k++) xn_bf[(p0+k)*LS + c] = f2bs((v[k] - m) * rv);
    }
    if (tid < 128){
        int br = tid >> 6, o = tid & 63;
        const float* W = br ? w2 : w1;
        float s = 0.f;
        for (int c = 0; c < 64; c++) s += W[o*64 + c];
        rowsumS[br][o] = s;
    }
    __syncthreads();

    #pragma unroll
    for (int br = 0; br < 2; br++){
        const float* W  = br ? w2  : w1;
        const float* cb = br ? cb2 : cb1;
        const float* gp = br ? g1b : g1a;
        const float* bp = br ? b1b : b1a;
        float* y = br ? y2 : y1;
        short8 a0 = load_w8(W + (size_t)(16*wq + col)*64 + 8*qd);
        short8 a1 = load_w8(W + (size_t)(16*wq + col)*64 + 32 + 8*qd);
        float cbv[4], rsv[4];
        #pragma unroll
        for (int r = 0; r < 4; r++){
            int o = 16*wq + 4*qd + r;
            cbv[r] = cb[o]; rsv[r] = rowsumS[br][o];
        }
        #pragma unroll
        for (int jn = 0; jn < 4; jn++){
            short8 bx0 = *(const short8*)&xn_bf[(16*jn + col)*LS + 8*qd];
            short8 bx1 = *(const short8*)&xn_bf[(16*jn + col)*LS + 32 + 8*qd];
            float4v acc = zf;
            acc = MFMA(a0, bx0, acc);
            acc = MFMA(a1, bx1, acc);
            int hw = hw0 + 16*jn + col;
            float gl = gp[hw], bl = bp[hw];
            #pragma unroll
            for (int r = 0; r < 4; r++){
                int o = 16*wq + 4*qd + r;
                y[(size_t)(b*64 + o)*HW + hw] = gl*acc[r] + bl*rsv[r] + cbv[r];
            }
        }
    }
}

// ---------------- Kernel 3: LN2 over (H,W) + exact GELU, in place ----------------
__global__ __launch_bounds__(256) void k_ln2gelu(float* __restrict__ y1, float* __restrict__ y2,
                                                 const float* __restrict__ g2a, const float* __restrict__ b2a,
                                                 const float* __restrict__ g2b, const float* __restrict__ b2b){
    int blk = blockIdx.x;                      // 2048: br*1024 + bc
    int br = blk >> 10; int bc = blk & 1023;
    float* y = br ? y2 : y1;
    const float* g  = br ? g2b : g2a;
    const float* bb = br ? b2b : b2a;
    float* p = y + (size_t)bc * HW;
    float s = 0.f, ss = 0.f;
    for (int i = threadIdx.x; i < HW; i += 256){
        float v = p[i]; s += v; ss += v*v;
    }
    __shared__ float rs[256], rss[256];
    __shared__ float smu, srinv;
    rs[threadIdx.x] = s; rss[threadIdx.x] = ss; __syncthreads();
    for (int st = 128; st > 0; st >>= 1){
        if (threadIdx.x < st){ rs[threadIdx.x] += rs[threadIdx.x+st]; rss[threadIdx.x] += rss[threadIdx.x+st]; }
        __syncthreads();
    }
    if (threadIdx.x == 0){
        float m = rs[0] * (1.f/HW);
        float v = rss[0] * (1.f/HW) - m*m;
        smu = m; srinv = rsqrtf(v + EPS);
    }
    __syncthreads();
    for (int i = threadIdx.x; i < HW; i += 256){
        float v = (p[i] - smu) * srinv * g[i] + bb[i];
        p[i] = gelu_exact(v);
    }
}

// ---------------- Kernel 4: attention + LAM + proj + channel-MLP (fused, MFMA) ----------------
// x1 (= y1 after ln2gelu) lives in d_out; final output written in place over x1.
__global__ __launch_bounds__(256) void k_attn(float* __restrict__ x1, const float* __restrict__ x2,
                                              const float* __restrict__ pos1, const float* __restrict__ pos2,
                                              const float* __restrict__ qw, const float* __restrict__ qb,
                                              const float* __restrict__ kvw, const float* __restrict__ kvb,
                                              const float* __restrict__ rpb, const float* __restrict__ gammap,
                                              const float* __restrict__ pw, const float* __restrict__ pb,
                                              const float* __restrict__ n2g, const float* __restrict__ n2b,
                                              const float* __restrict__ fw1, const float* __restrict__ fb1,
                                              const float* __restrict__ fw2, const float* __restrict__ fb2){
    // XCD swizzle: bits [2:0]=hy[2:0], [3]=wx[0], [7:4]=b, [8]=hy[3], [11:9]=wx[3:1]
    // => the two windows sharing each 64B line (wx even/odd) are 8 apart in
    //    blockIdx (same XCD under %8 round-robin) and issue back-to-back.
    int B = blockIdx.x;
    int hy = (B & 7) | ((B >> 5) & 8);
    int wx = (((B >> 9) & 7) << 1) | ((B >> 3) & 1);
    int b  = (B >> 4) & 15;

    __shared__ __align__(16) char smem[51744];
    short* bufA = (short*)smem;                    // 9216  X2w -> X1w
    short* bufK = (short*)(smem + 9216);           // 9216  K -> O2
    short* bufV = (short*)(smem + 18432);          // 9216  VT -> OT
    short* bufQ = (short*)(smem + 27648);          // 9216  Q -> h1 (MLP)
    short* bufP = (short*)(smem + 36864);          // 9216  P -> XO -> tn (MLP)
    float* rpb_lds = (float*)(smem + 46080);       // 3600
    float* energyS = (float*)(smem + 49696);       // 1024
    short* soft_bf = (short*)(smem + 50720);       // 1024
    // MLP-tail aliases (all source regions dead by then):
    float* XOf  = (float*)smem;                    // 64x65 fp32 (A+K regions)
    float* sumS = (float*)(smem + 49696);          // 4x64 (energy)
    float* sqS  = (float*)(smem + 50720);          // 4x64 (soft)
    float* muS  = (float*)(smem + 46080);          // 64   (rpb)
    float* rinvS= (float*)(smem + 46336);          // 64

    const int tid = threadIdx.x;
    const int wq = tid >> 6, lane = tid & 63, qd = lane >> 4, col = lane & 15;
    size_t base = (size_t)b * NPLANE;
    #define HWOF(t) ((hy*8 + ((t)>>3))*128 + wx*8 + ((t)&7))

    const float4v zf = {0.f,0.f,0.f,0.f};
    const short8 zero8 = {0,0,0,0,0,0,0,0};

    for (int i = tid; i < 900; i += 256) rpb_lds[i] = rpb[i];

    // ---- load X2 (+pos2) -> bufA ----
    for (int i = tid; i < 1024; i += 256){
        int c = i >> 4, t0 = (i & 15) * 4;
        float4v v = *(const float4v*)(x2 + base + (size_t)c*HW + HWOF(t0));
        #pragma unroll
        for (int k = 0; k < 4; k++)
            bufA[(t0+k)*LS + c] = f2bs(v[k] + pos2[(t0+k)*64 + c]);
    }
    __syncthreads();

    // ---- VT = Wv · X2^T ----
    {
        float bvr[4];
        #pragma unroll
        for (int r = 0; r < 4; r++) bvr[r] = kvb[64 + 16*wq + 4*qd + r];
        short8 a0 = load_w8(kvw + (size_t)(64 + 16*wq + col)*64 + 8*qd);
        short8 a1 = load_w8(kvw + (size_t)(64 + 16*wq + col)*64 + 32 + 8*qd);
        #pragma unroll
        for (int jn = 0; jn < 4; jn++){
            int u = 16*jn + col;
            short8 b0 = *(const short8*)&bufA[u*LS + 8*qd];
            short8 b1 = *(const short8*)&bufA[u*LS + 32 + 8*qd];
            float4v acc = zf;
            acc = MFMA(a0, b0, acc);
            acc = MFMA(a1, b1, acc);
            #pragma unroll
            for (int r = 0; r < 4; r++)
                bufV[(16*wq + 4*qd + r)*LS + u] = f2bs(acc[r] + bvr[r]);
        }
    }
    // ---- K = X2 · Wk^T ----
    {
        short8 ax0 = *(const short8*)&bufA[(16*wq + col)*LS + 8*qd];
        short8 ax1 = *(const short8*)&bufA[(16*wq + col)*LS + 32 + 8*qd];
        #pragma unroll
        for (int jn = 0; jn < 4; jn++){
            int co = 16*jn + col;
            short8 b0 = load_w8(kvw + (size_t)co*64 + 8*qd);
            short8 b1 = load_w8(kvw + (size_t)co*64 + 32 + 8*qd);
            float4v acc = zf;
            acc = MFMA(ax0, b0, acc);
            acc = MFMA(ax1, b1, acc);
            float kb = kvb[co];
            #pragma unroll
            for (int r = 0; r < 4; r++)
                bufK[(16*wq + 4*qd + r)*LS + co] = f2bs(acc[r] + kb);
        }
    }
    __syncthreads();

    // ---- load X1 (+pos1) -> bufA ----
    for (int i = tid; i < 1024; i += 256){
        int c = i >> 4, t0 = (i & 15) * 4;
        float4v v = *(const float4v*)(x1 + base + (size_t)c*HW + HWOF(t0));
        #pragma unroll
        for (int k = 0; k < 4; k++)
            bufA[(t0+k)*LS + c] = f2bs(v[k] + pos1[(t0+k)*64 + c]);
    }
    __syncthreads();

    // ---- Q = 0.25 * (X1 · Wq^T + qb) ----
    {
        short8 ax0 = *(const short8*)&bufA[(16*wq + col)*LS + 8*qd];
        short8 ax1 = *(const short8*)&bufA[(16*wq + col)*LS + 32 + 8*qd];
        #pragma unroll
        for (int jn = 0; jn < 4; jn++){
            int co = 16*jn + col;
            short8 b0 = load_w8(qw + (size_t)co*64 + 8*qd);
            short8 b1 = load_w8(qw + (size_t)co*64 + 32 + 8*qd);
            float4v acc = zf;
            acc = MFMA(ax0, b0, acc);
            acc = MFMA(ax1, b1, acc);
            float qbv = qb[co];
            #pragma unroll
            for (int r = 0; r < 4; r++)
                bufQ[(16*wq + 4*qd + r)*LS + co] = f2bs((acc[r] + qbv) * 0.25f);
        }
    }
    __syncthreads();

    int idx_t[4][4];
    #pragma unroll
    for (int jn = 0; jn < 4; jn++){
        int u = 16*jn + col; int uy = u >> 3, ux = u & 7;
        #pragma unroll
        for (int r = 0; r < 4; r++){
            int t = 16*wq + 4*qd + r;
            idx_t[jn][r] = ((t>>3) - uy + 7)*15 + ((t&7) - ux + 7);
        }
    }

    // ---- head loop: S -> softmax -> P -> PV -> OT/O2 ----
    for (int h = 0; h < 4; h++){
        short8 aq = *(const short8*)&bufQ[(16*wq + col)*LS + h*16 + (qd & 1)*8];
        if (qd >= 2) aq = zero8;
        float4v acc_s[4];
        #pragma unroll
        for (int jn = 0; jn < 4; jn++){
            int u = 16*jn + col;
            short8 bk = *(const short8*)&bufK[u*LS + h*16 + (qd & 1)*8];
            acc_s[jn] = MFMA(aq, bk, zf);
        }
        float pr[4][4];
        #pragma unroll
        for (int jn = 0; jn < 4; jn++)
            #pragma unroll
            for (int r = 0; r < 4; r++)
                pr[jn][r] = acc_s[jn][r] + rpb_lds[idx_t[jn][r]*4 + h];
        #pragma unroll
        for (int r = 0; r < 4; r++){
            float m = fmaxf(fmaxf(pr[0][r], pr[1][r]), fmaxf(pr[2][r], pr[3][r]));
            m = fmaxf(m, __shfl_xor(m, 1)); m = fmaxf(m, __shfl_xor(m, 2));
            m = fmaxf(m, __shfl_xor(m, 4)); m = fmaxf(m, __shfl_xor(m, 8));
            float s = 0.f;
            #pragma unroll
            for (int jn = 0; jn < 4; jn++){ pr[jn][r] = __expf(pr[jn][r] - m); s += pr[jn][r]; }
            s += __shfl_xor(s, 1); s += __shfl_xor(s, 2);
            s += __shfl_xor(s, 4); s += __shfl_xor(s, 8);
            float rc = 1.f / s;
            #pragma unroll
            for (int jn = 0; jn < 4; jn++)
                bufP[(16*wq + 4*qd + r)*LS + 16*jn + col] = f2bs(pr[jn][r] * rc);
        }
        __syncthreads();
        short8 ap0 = *(const short8*)&bufP[(16*wq + col)*LS + 8*qd];
        short8 ap1 = *(const short8*)&bufP[(16*wq + col)*LS + 32 + 8*qd];
        short8 bv0 = *(const short8*)&bufV[(h*16 + col)*LS + 8*qd];
        short8 bv1 = *(const short8*)&bufV[(h*16 + col)*LS + 32 + 8*qd];
        float4v acc_o = zf;
        acc_o = MFMA(ap0, bv0, acc_o);
        acc_o = MFMA(ap1, bv1, acc_o);
        __syncthreads();
        short4v ot;
        #pragma unroll
        for (int r = 0; r < 4; r++) ot[r] = f2bs(acc_o[r]);
        *(short4v*)&bufV[(h*16 + col)*LS + 16*wq + 4*qd] = ot;
        #pragma unroll
        for (int r = 0; r < 4; r++)
            bufK[(16*wq + 4*qd + r)*LS + h*16 + col] = ot[r];
    }
    __syncthreads();

    // ---- energy = Y Y^T (16x16, K=256) ----
    {
        float4v acc_e = zf;
        #pragma unroll
        for (int h = 0; h < 4; h++){
            short8 f0 = *(const short8*)&bufV[(h*16 + col)*LS + 8*qd];
            short8 f1 = *(const short8*)&bufV[(h*16 + col)*LS + 32 + 8*qd];
            acc_e = MFMA(f0, f0, acc_e);
            acc_e = MFMA(f1, f1, acc_e);
        }
        if (wq == 0){
            #pragma unroll
            for (int r = 0; r < 4; r++) energyS[(4*qd + r)*16 + col] = acc_e[r];
        }
    }
    __syncthreads();
    if (tid < 16){
        int i = tid; float m = -1e30f;
        for (int j = 0; j < 16; j++) m = fmaxf(m, energyS[i*16 + j]);
        float s = 0.f; float e[16];
        for (int j = 0; j < 16; j++){ e[j] = __expf(energyS[i*16 + j] - m); s += e[j]; }
        float rc = 1.f / s;
        for (int j = 0; j < 16; j++) soft_bf[i*32 + j] = f2bs(e[j] * rc);
        for (int j = 0; j < 16; j++) soft_bf[i*32 + 16 + j] = 0;
    }
    __syncthreads();

    // ---- lam (per wave: head h=wq) + assemble XO -> bufP ----
    {
        int h = wq;
        float gam = gammap[0];
        short8 asf = *(const short8*)&soft_bf[col*32 + 8*qd];
        #pragma unroll
        for (int jn = 0; jn < 4; jn++){
            int t = 16*jn + col;
            short8 bo = *(const short8*)&bufK[t*LS + h*16 + (qd & 1)*8];
            float4v acc = MFMA(asf, bo, zf);
            short4v qv = *(const short4v*)&bufQ[t*LS + h*16 + 4*qd];
            short4v xv = *(const short4v*)&bufA[t*LS + h*16 + 4*qd];
            short4v pk;
            #pragma unroll
            for (int r = 0; r < 4; r++){
                float ot = bs2f(bufV[(h*16 + 4*qd + r)*LS + t]);
                float xo = gam*acc[r] + ot + bs2f(qv[r]) + bs2f(xv[r]);
                pk[r] = f2bs(xo);
            }
            *(short4v*)&bufP[t*LS + h*16 + 4*qd] = pk;
        }
    }
    __syncthreads();

    // ---- proj: XO · Wp^T + pb -> XOf (fp32 LDS, aliases bufA+bufK) ----
    {
        short8 a0 = *(const short8*)&bufP[(16*wq + col)*LS + 8*qd];
        short8 a1 = *(const short8*)&bufP[(16*wq + col)*LS + 32 + 8*qd];
        #pragma unroll
        for (int jn = 0; jn < 4; jn++){
            int c = 16*jn + col;
            short8 b0 = load_w8(pw + (size_t)c*64 + 8*qd);
            short8 b1 = load_w8(pw + (size_t)c*64 + 32 + 8*qd);
            float4v acc = zf;
            acc = MFMA(a0, b0, acc);
            acc = MFMA(a1, b1, acc);
            float pbv = pb[c];
            #pragma unroll
            for (int r = 0; r < 4; r++)
                XOf[(16*wq + 4*qd + r)*65 + c] = acc[r] + pbv;
        }
    }
    __syncthreads();

    // ================= fused channel-MLP =================
    {
        int p = tid & 63, qg = tid >> 6;
        float s = 0.f, ss = 0.f;
        #pragma unroll
        for (int j = 0; j < 16; j++){ float v = XOf[p*65 + qg*16 + j]; s += v; ss += v*v; }
        sumS[qg*64 + p] = s; sqS[qg*64 + p] = ss;
    }
    __syncthreads();
    if (tid < 64){
        float s  = sumS[tid] + sumS[64+tid] + sumS[128+tid] + sumS[192+tid];
        float ss = sqS[tid]  + sqS[64+tid]  + sqS[128+tid]  + sqS[192+tid];
        float m = s * (1.f/64.f);
        float var = ss * (1.f/64.f) - m*m;
        muS[tid] = m; rinvS[tid] = rsqrtf(var + EPS);
    }
    __syncthreads();
    // tn -> bufP (bf16)
    {
        int p = tid & 63, qg = tid >> 6;
        float m = muS[p], rv = rinvS[p];
        #pragma unroll
        for (int j = 0; j < 16; j++){
            int c = qg*16 + j;
            bufP[p*LS + c] = f2bs((XOf[p*65 + c] - m) * rv * n2g[c] + n2b[c]);
        }
    }
    __syncthreads();
    // GEMM1: h1 = gelu(tn @ W1^T + fb1) -> bufQ
    {
        short8 a0 = *(const short8*)&bufP[(16*wq + col)*LS + 8*qd];
        short8 a1 = *(const short8*)&bufP[(16*wq + col)*LS + 32 + 8*qd];
        #pragma unroll
        for (int jn = 0; jn < 4; jn++){
            int j = 16*jn + col;
            short8 f0 = load_w8(fw1 + (size_t)j*64 + 8*qd);
            short8 f1 = load_w8(fw1 + (size_t)j*64 + 32 + 8*qd);
            float4v acc = zf;
            acc = MFMA(a0, f0, acc);
            acc = MFMA(a1, f1, acc);
            float bv = fb1[j];
            #pragma unroll
            for (int r = 0; r < 4; r++)
                bufQ[(16*wq + 4*qd + r)*LS + j] = f2bs(gelu_exact(acc[r] + bv));
        }
    }
    __syncthreads();
    // GEMM2: out = xo + h1 @ W2^T + fb2 -> global (in place over x1)
    {
        short8 a0 = *(const short8*)&bufQ[(16*wq + col)*LS + 8*qd];
        short8 a1 = *(const short8*)&bufQ[(16*wq + col)*LS + 32 + 8*qd];
        #pragma unroll
        for (int jn = 0; jn < 4; jn++){
            int c2 = 16*jn + col;
            short8 f0 = load_w8(fw2 + (size_t)c2*64 + 8*qd);
            short8 f1 = load_w8(fw2 + (size_t)c2*64 + 32 + 8*qd);
            float4v acc = zf;
            acc = MFMA(a0, f0, acc);
            acc = MFMA(a1, f1, acc);
            float bv = fb2[c2];
            float4v ov;
            #pragma unroll
            for (int r = 0; r < 4; r++)
                ov[r] = acc[r] + bv + XOf[(16*wq + 4*qd + r)*65 + c2];
            int t0 = 16*wq + 4*qd;
            *(float4v*)(x1 + base + (size_t)c2*HW + HWOF(t0)) = ov;
        }
    }
    #undef HWOF
}

extern "C" void kernel_launch(void* const* d_in, const int* in_sizes, int n_in,
                              void* d_out, int out_size, void* d_ws, size_t ws_size,
                              hipStream_t stream){
    const float* x        = (const float*)d_in[0];
    const float* l1_g1    = (const float*)d_in[1];
    const float* l1_b1    = (const float*)d_in[2];
    const float* l1_cw    = (const float*)d_in[3];
    const float* l1_cb    = (const float*)d_in[4];
    const float* l1_g2    = (const float*)d_in[5];
    const float* l1_b2    = (const float*)d_in[6];
    const float* l2_g1    = (const float*)d_in[7];
    const float* l2_b1    = (const float*)d_in[8];
    const float* l2_cw    = (const float*)d_in[9];
    const float* l2_cb    = (const float*)d_in[10];
    const float* l2_g2    = (const float*)d_in[11];
    const float* l2_b2    = (const float*)d_in[12];
    const float* pos1     = (const float*)d_in[13];
    const float* pos2     = (const float*)d_in[14];
    const float* q_w      = (const float*)d_in[15];
    const float* q_b      = (const float*)d_in[16];
    const float* kv_w     = (const float*)d_in[17];
    const float* kv_b     = (const float*)d_in[18];
    const float* rpb      = (const float*)d_in[19];
    const float* gamma    = (const float*)d_in[20];
    const float* proj_w   = (const float*)d_in[21];
    const float* proj_b   = (const float*)d_in[22];
    const float* norm2_g  = (const float*)d_in[23];
    const float* norm2_b  = (const float*)d_in[24];
    const float* fc1_w    = (const float*)d_in[25];
    const float* fc1_b    = (const float*)d_in[26];
    const float* fc2_w    = (const float*)d_in[27];
    const float* fc2_b    = (const float*)d_in[28];

    float* out = (float*)d_out;                // y1 -> final, in place

    float* y2    = (float*)d_ws;               // 16*NPLANE floats (67 MB)
    float* mu1   = y2 + (size_t)16*NPLANE;
    float* rinv1 = mu1 + 1024;

    k_stats  <<<1024, 256, 0, stream>>>(x, mu1, rinv1);
    k_conv   <<<4096, 256, 0, stream>>>(x, mu1, rinv1,
                                        l1_g1, l1_b1, l1_cw, l1_cb,
                                        l2_g1, l2_b1, l2_cw, l2_cb, out, y2);
    k_ln2gelu<<<2048, 256, 0, stream>>>(out, y2, l1_g2, l1_b2, l2_g2, l2_b2);
    k_attn   <<<4096, 256, 0, stream>>>(out, y2,
                                        pos1, pos2, q_w, q_b, kv_w, kv_b,
                                        rpb, gamma, proj_w, proj_b,
                                        norm2_g, norm2_b, fc1_w, fc1_b, fc2_w, fc2_b);
}